// Round 3
// 338.507 us; speedup vs baseline: 1.0110x; 1.0110x over previous
//
#include <hip/hip_runtime.h>
#include <hip/hip_bf16.h>
#include <stdint.h>

#define BATCH   2048
#define NF      16
#define EMBED   256
#define NPAIRS  120
#define OUTROW  (NPAIRS*EMBED)   /* 30720 */
#define EMBROW  (NF*EMBED)       /* 4096  */

typedef __attribute__((ext_vector_type(8))) __bf16 bf16x8;
typedef __attribute__((ext_vector_type(4))) float  f32x4;

typedef __attribute__((address_space(3))) void       lds_void;
typedef const __attribute__((address_space(1))) void g_void;

__device__ __forceinline__ unsigned short f2bf(float f) {
    unsigned u = __float_as_uint(f);
    u += 0x7FFF + ((u >> 16) & 1);   // round-to-nearest-even
    return (unsigned short)(u >> 16);
}

__device__ __forceinline__ void pair_rc(int p, int& r, int& c) {
    int rr = 0, base = 0;
    while (p >= base + (NF - 1 - rr)) { base += NF - 1 - rr; ++rr; }
    r = rr; c = rr + 1 + (p - base);
}

// ---------------- prepass 1: emb (B,NF,E) fp32 -> embp[f][e/8][b][8] bf16 ----------------
__global__ __launch_bounds__(256) void emb_permute(const float* __restrict__ emb,
                                                   unsigned short* __restrict__ embp) {
    __shared__ float tile[64][65];
    const int b0 = blockIdx.x * 64;
    const int e0 = blockIdx.y * 64;
    const int f  = blockIdx.z;
    const int t  = threadIdx.x;
#pragma unroll
    for (int rnd = 0; rnd < 4; ++rnd) {
        int bl = rnd * 16 + (t >> 4);
        int el = (t & 15) * 4;
        const float4 v = *(const float4*)(emb + (size_t)(b0 + bl) * EMBROW + f * EMBED + e0 + el);
        tile[bl][el] = v.x; tile[bl][el + 1] = v.y; tile[bl][el + 2] = v.z; tile[bl][el + 3] = v.w;
    }
    __syncthreads();
#pragma unroll
    for (int rnd = 0; rnd < 2; ++rnd) {
        int ec = rnd * 4 + (t >> 6);   // 0..7 within tile
        int bl = t & 63;
        unsigned short h[8];
#pragma unroll
        for (int i = 0; i < 8; ++i) h[i] = f2bf(tile[bl][ec * 8 + i]);
        uint4 w;
        w.x = h[0] | ((unsigned)h[1] << 16);
        w.y = h[2] | ((unsigned)h[3] << 16);
        w.z = h[4] | ((unsigned)h[5] << 16);
        w.w = h[6] | ((unsigned)h[7] << 16);
        *(uint4*)(embp + (size_t)f * (32u * BATCH * 8) + (size_t)(e0 / 8 + ec) * (BATCH * 8)
                        + (size_t)(b0 + bl) * 8) = w;
    }
}

// ---------------- prepass 2: weight (P,E,E) fp32 -> wtp[p][e/8][f][8] bf16 ----------------
__global__ __launch_bounds__(256) void wt_permute(const float* __restrict__ wt,
                                                  unsigned short* __restrict__ wtp) {
    __shared__ float tile[64][65];   // [e][f]
    const int e0 = blockIdx.x * 64;
    const int f0 = blockIdx.y * 64;
    const int p  = blockIdx.z;
    const int t  = threadIdx.x;
#pragma unroll
    for (int rnd = 0; rnd < 4; ++rnd) {
        int el = rnd * 16 + (t >> 4);
        int fl = (t & 15) * 4;
        const float4 v = *(const float4*)(wt + (size_t)p * (EMBED * EMBED) + (size_t)(e0 + el) * EMBED + f0 + fl);
        tile[el][fl] = v.x; tile[el][fl + 1] = v.y; tile[el][fl + 2] = v.z; tile[el][fl + 3] = v.w;
    }
    __syncthreads();
#pragma unroll
    for (int rnd = 0; rnd < 2; ++rnd) {
        int ec = rnd * 4 + (t >> 6);   // 0..7: e-chunk within tile
        int fl = t & 63;
        unsigned short h[8];
#pragma unroll
        for (int i = 0; i < 8; ++i) h[i] = f2bf(tile[ec * 8 + i][fl]);   // row read, conflict-free
        uint4 w;
        w.x = h[0] | ((unsigned)h[1] << 16);
        w.y = h[2] | ((unsigned)h[3] << 16);
        w.z = h[4] | ((unsigned)h[5] << 16);
        w.w = h[6] | ((unsigned)h[7] << 16);
        *(uint4*)(wtp + (size_t)p * (EMBED * EMBED) + (size_t)(e0 / 8 + ec) * (EMBED * 8)
                       + (size_t)(f0 + fl) * 8) = w;
    }
}

// ---------------- main: per (pair, mblk, nblk): 128x128 tile of C = A_r @ W_p, fused *q + bias ----------------
// Triple-buffered staging, counted vmcnt + raw s_barrier.
// CRITICAL (rule #18 generalized): every barrier DRAINS lgkmcnt first.
// hipcc sinks register-only MFMAs (and their backend-inserted lgkm waits) past
// volatile-asm barriers, so without an explicit lgkmcnt(0) a wave can signal
// s_barrier with its ds_reads still in flight -> next STAGE overwrites the
// buffer mid-read (the r1/r2 race, absmax ~3.3). __syncthreads() has this
// drain built in; the raw-barrier port must add it back.
// vm ledger (stage Sk -> buf k%3; 4 vm-ops per stage per thread):
//   prologue: S0,S1,S2 issued (order-pinned); vmcnt(0); bar
//   ki=1: +S3 (4 out)  vm(8) noop   ki=2: +S4 (8 out)  vm(8) noop
//   ki=3: +S5 (12)     vm(8)->S3    ki=4: +S6 (12)     vm(8)->S4
//   ki=5: +S7 (12)     vm(8)->S5    ki=6: (8)          vm(4)->S6
//   ki=7: (4)          vm(0)->S7
// WAR: buf b read at ki, overwritten at ki+1 -> separated by one DRAINED barrier.
// Epilogue ep slab overlays the staging buffers (after full __syncthreads drain).
__global__ __launch_bounds__(256, 3) void bilinear_main(
        const float* __restrict__ emb, const float* __restrict__ bias,
        const unsigned short* __restrict__ embp, const unsigned short* __restrict__ wtp,
        float* __restrict__ out) {
    __shared__ __align__(16) unsigned short a_lds[3][4096];  // [buf][kc*128*8] bf16, 24KB
    __shared__ __align__(16) unsigned short b_lds[3][4096];  // 24KB

    const int nblk = blockIdx.x, mblk = blockIdx.y, p = blockIdx.z;
    int r, c; pair_rc(p, r, c);
    const int m0 = mblk * 128, n0 = nblk * 128;
    const int t = threadIdx.x;
    const int wave = t >> 6, lane = t & 63;
    const int wm = (wave >> 1) * 64, wn = (wave & 1) * 64;
    const int kq = lane >> 4, l15 = lane & 15;

    const unsigned short* a_base = embp + (size_t)r * (32u * BATCH * 8);
    const unsigned short* b_base = wtp + (size_t)p * (EMBED * EMBED);

    f32x4 acc[4][4] = {};

    // 4 global_load_lds (vmcnt ops) per STAGE per thread
#define STAGE(buf, ki)                                                              \
    {                                                                               \
        _Pragma("unroll")                                                           \
        for (int i = 0; i < 2; ++i) {                                               \
            int q  = i * 256 + t;            /* chunk = kc*128 + rowlocal */        \
            int kc = q >> 7, xl = q & 127;                                          \
            const unsigned short* ga = a_base + (size_t)((ki) * 4 + kc) * (BATCH * 8) \
                                             + (size_t)(m0 + xl) * 8;               \
            __builtin_amdgcn_global_load_lds((g_void*)ga,                           \
                (lds_void*)(&a_lds[buf][0] + q * 8), 16, 0, 0);                     \
            const unsigned short* gb = b_base + (size_t)((ki) * 4 + kc) * (EMBED * 8) \
                                             + (size_t)(n0 + xl) * 8;               \
            __builtin_amdgcn_global_load_lds((g_void*)gb,                           \
                (lds_void*)(&b_lds[buf][0] + q * 8), 16, 0, 0);                     \
        }                                                                           \
    }

#define COMPUTE(buf)                                                                \
    {                                                                               \
        bf16x8 af[4], bfr[4];                                                       \
        _Pragma("unroll")                                                           \
        for (int i = 0; i < 4; ++i)                                                 \
            af[i] = *(const bf16x8*)(&a_lds[buf][0] + (kq * 128 + wm + i * 16 + l15) * 8); \
        _Pragma("unroll")                                                           \
        for (int j = 0; j < 4; ++j)                                                 \
            bfr[j] = *(const bf16x8*)(&b_lds[buf][0] + (kq * 128 + wn + j * 16 + l15) * 8); \
        _Pragma("unroll")                                                           \
        for (int i = 0; i < 4; ++i)                                                 \
            _Pragma("unroll")                                                       \
            for (int j = 0; j < 4; ++j)                                             \
                acc[i][j] = __builtin_amdgcn_mfma_f32_16x16x32_bf16(af[i], bfr[j], acc[i][j], 0, 0, 0); \
    }

#define FENCE asm volatile("" ::: "memory")
#define SBAR  __builtin_amdgcn_sched_barrier(0)
// Drained barrier: lgkmcnt(0) BEFORE s_barrier so all of this wave's ds_reads
// have completed before it signals; sched_barrier pins so nothing crosses.
#define BAR()                                                                       \
    {                                                                               \
        SBAR;                                                                       \
        asm volatile("s_waitcnt lgkmcnt(0)" ::: "memory");                          \
        SBAR;                                                                       \
        __builtin_amdgcn_s_barrier();                                               \
        SBAR;                                                                       \
    }
#define WAITVM(N)                                                                   \
    {                                                                               \
        SBAR;                                                                       \
        asm volatile("s_waitcnt vmcnt(" #N ")" ::: "memory");                       \
        SBAR;                                                                       \
    }

    // prologue: 3 stages issued (order-pinned), then ONE full drain
    STAGE(0, 0) FENCE; SBAR;
    STAGE(1, 1) FENCE; SBAR;
    STAGE(2, 2) FENCE; SBAR;
    WAITVM(0) BAR();

    // K = 256, BK = 32 -> 8 steps, buf = ki % 3
                           COMPUTE(0) BAR();   // ki=0
    STAGE(0, 3) WAITVM(8) BAR(); COMPUTE(1) BAR();   // ki=1
    STAGE(1, 4) WAITVM(8) BAR(); COMPUTE(2) BAR();   // ki=2
    STAGE(2, 5) WAITVM(8) BAR(); COMPUTE(0) BAR();   // ki=3
    STAGE(0, 6) WAITVM(8) BAR(); COMPUTE(1) BAR();   // ki=4
    STAGE(1, 7) WAITVM(8) BAR(); COMPUTE(2) BAR();   // ki=5
                WAITVM(4) BAR(); COMPUTE(0) BAR();   // ki=6
                WAITVM(0) BAR(); COMPUTE(1)          // ki=7

    __syncthreads();   // full drain: all waves done with staging LDS before ep overlay

    // ---- epilogue: LDS-transpose per wave slab -> f32x4 q loads, f32x4 NT stores ----
    // out[m, p, n] = acc * emb[m, c, n] + bias[p, n]
    // ep slab overlays a_lds (16.9KB <= 24KB), per-wave private, in-order LDS pipe.
    float* epw = (float*)(&a_lds[0][0]) + wave * (16 * 66);
    const int lrow4 = lane >> 4;         // 0..3
    const int lcol  = (lane & 15) * 4;   // 0,4,...,60 (4 consecutive cols per thread)
    const f32x4 bv = *(const f32x4*)(bias + p * EMBED + n0 + wn + lcol);

#pragma unroll
    for (int i = 0; i < 4; ++i) {
        // scatter C/D fragments into slab: row=(lane>>4)*4+reg, col=j*16+l15
#pragma unroll
        for (int j = 0; j < 4; ++j)
#pragma unroll
            for (int reg = 0; reg < 4; ++reg)
                epw[(kq * 4 + reg) * 66 + j * 16 + l15] = acc[i][j][reg];
        // gather rows back vectorized (wave-private slab: in-order LDS pipe, no barrier)
#pragma unroll
        for (int rr = 0; rr < 4; ++rr) {
            const int lrow = rr * 4 + lrow4;              // 0..15
            const f32x4 v = *(const f32x4*)&epw[lrow * 66 + lcol];
            const int row  = m0 + wm + i * 16 + lrow;
            const f32x4 q = *(const f32x4*)(emb + (size_t)row * EMBROW + c * EMBED + n0 + wn + lcol);
            f32x4 o = v * q + bv;
            __builtin_nontemporal_store(o, (f32x4*)(out + (size_t)row * OUTROW + p * EMBED + n0 + wn + lcol));
        }
    }
#undef STAGE
#undef COMPUTE
#undef FENCE
#undef SBAR
#undef BAR
#undef WAITVM
}

extern "C" void kernel_launch(void* const* d_in, const int* in_sizes, int n_in,
                              void* d_out, int out_size, void* d_ws, size_t ws_size,
                              hipStream_t stream) {
    const float* emb    = (const float*)d_in[0];
    const float* weight = (const float*)d_in[1];
    const float* bias   = (const float*)d_in[2];
    float* out = (float*)d_out;

    // workspace: wtp (120*256*256 bf16 = 15,728,640 B) then embp (16*32*2048*8 bf16 = 16,777,216 B)
    unsigned short* wtp  = (unsigned short*)d_ws;
    unsigned short* embp = (unsigned short*)((char*)d_ws + 15728640);

    wt_permute<<<dim3(4, 4, NPAIRS), 256, 0, stream>>>(weight, wtp);
    emb_permute<<<dim3(BATCH / 64, EMBED / 64, NF), 256, 0, stream>>>(emb, embp);
    bilinear_main<<<dim3(2, BATCH / 128, NPAIRS), 256, 0, stream>>>(emb, bias, embp, wtp, out);
}